// Round 8
// baseline (242.952 us; speedup 1.0000x reference)
//
#include <hip/hip_runtime.h>
#include <hip/hip_bf16.h>

#define TOK   16384       // B*N = 4*4096
#define KD    1024        // DIM
#define NQKV  3072
#define SEQL  4096
#define ATT_SCALE 0.125f  // 64^-0.5

typedef __attribute__((ext_vector_type(4))) float f32x4;
typedef __attribute__((ext_vector_type(8))) short bf16x8;

__device__ __forceinline__ unsigned short f2b(float f){
    union { float f; unsigned u; } x; x.f = f;
    return (unsigned short)((x.u + 0x7FFFu + ((x.u >> 16) & 1u)) >> 16);
}
__device__ __forceinline__ float b2f(unsigned short s){
    union { unsigned u; float f; } x; x.u = ((unsigned)s) << 16;
    return x.f;
}
__device__ __forceinline__ bf16x8 lds8(const unsigned short* p){
    union { uint4 u; bf16x8 v; } t; t.u = *(const uint4*)p; return t.v;
}
__device__ __forceinline__ void glds16(const void* g, void* l){
    __builtin_amdgcn_global_load_lds((const __attribute__((address_space(1))) unsigned*)g,
                                     (__attribute__((address_space(3))) unsigned*)l, 16, 0, 0);
}

// fp32 -> bf16 convert, 8 elems/thread
__global__ __launch_bounds__(256) void cvt_kernel(const float* __restrict__ in,
                                                  unsigned short* __restrict__ out, int n)
{
    int i = (blockIdx.x * 256 + threadIdx.x) * 8;
    if (i >= n) return;
    float4 a = *(const float4*)(in + i);
    float4 b = *(const float4*)(in + i + 4);
    union { unsigned short u[8]; uint4 v; } t;
    t.u[0]=f2b(a.x); t.u[1]=f2b(a.y); t.u[2]=f2b(a.z); t.u[3]=f2b(a.w);
    t.u[4]=f2b(b.x); t.u[5]=f2b(b.y); t.u[6]=f2b(b.z); t.u[7]=f2b(b.w);
    *(uint4*)(out + i) = t.v;
}

// ===== 256x256 GEMM — faithful m201 8-phase template =====
// 8 phases per iter covering 2 K-tiles (even tile -> dbuf0, odd -> dbuf1).
// Phase = { ds_reads ; stage 1 half-tile ; barrier ; lgkm(0) ; setprio(1) ;
//           16 MFMA ; setprio(0) ; [vmcnt(6) at ph4/ph8] ; barrier }.
// Stage schedule (free-after-read verified):
//   ph1: d1.Ah1(2J+1)  ph2: d0.Ah0(2J+2)  ph3: d0.Bh0(2J+2)  ph4: d0.Bh1(2J+2)
//   ph5: d0.Ah1(2J+2)  ph6: d1.Ah0(2J+3)  ph7: d1.Bh0(2J+3)  ph8: d1.Bh1(2J+3)
// vmcnt(6) at ph4 retires prev ph6-8 + ph1 (tile 2J+1 complete before ph5);
// vmcnt(6) at ph8 retires ph2-5 (tile 2J+2 complete before next ph1).
template<bool OUT_BF16>
__global__ __launch_bounds__(512, 2) void gemm256(const unsigned short* __restrict__ A,
        const unsigned short* __restrict__ Bw, const float* __restrict__ bias,
        void* __restrict__ Cp, int Nn)
{
    extern __shared__ unsigned short smem[];
    unsigned short* As = smem;            // [2][256][64] shorts
    unsigned short* Bs = smem + 32768;

    const int tid = threadIdx.x, lane = tid & 63;
    const int w = tid >> 6, wm = w >> 2, wn = w & 3;
    const int rl = lane & 15, kslot = lane >> 4;

    // T1: bijective XCD swizzle (nwg % 8 == 0 for both GEMMs)
    const int gx = gridDim.x;
    const int nwg = gx * gridDim.y;
    int id = blockIdx.y * gx + blockIdx.x;
    id = (id & 7) * (nwg >> 3) + (id >> 3);
    const int cBase = (id % gx) * 256;
    const int mBase = (id / gx) * 256;

    // staging: thread covers LDS row u (per 64-row chunk), seg tid&7;
    // global source seg pre-swizzled with (LDS row)&7 = u&7.
    const int u = tid >> 3;
    const int seg8 = ((tid & 7) ^ (u & 7)) * 8;
    const unsigned short* Ag = A  + (size_t)(mBase + u) * KD + seg8;
    const unsigned short* Bg = Bw + (size_t)(cBase + (u >> 4) * 64 + (u & 15)) * KD + seg8;

    // fragment read offsets (shorts)
    const int arow = (wm * 16 + rl) * 64;      // + m*2048 (+8192 upper half)
    const int brow = (wn * 16 + rl) * 64;      // + n*4096
    const int psg0 = (kslot ^ (rl & 7)) * 8;
    const int psg1 = ((kslot + 4) ^ (rl & 7)) * 8;

    f32x4 acc[8][4];
    #pragma unroll
    for (int m = 0; m < 8; m++)
        #pragma unroll
        for (int n = 0; n < 4; n++) acc[m][n] = (f32x4)0.f;

#define STAGE_AH0(bb, kk) { glds16(Ag + (kk),            As + (bb)*16384 + tid*8); \
                            glds16(Ag + 64*KD + (kk),    As + (bb)*16384 + 4096  + tid*8); }
#define STAGE_AH1(bb, kk) { glds16(Ag + 128*KD + (kk),   As + (bb)*16384 + 8192  + tid*8); \
                            glds16(Ag + 192*KD + (kk),   As + (bb)*16384 + 12288 + tid*8); }
#define STAGE_BH0(bb, kk) { glds16(Bg + (kk),            Bs + (bb)*16384 + tid*8); \
                            glds16(Bg + 16*KD + (kk),    Bs + (bb)*16384 + 4096  + tid*8); }
#define STAGE_BH1(bb, kk) { glds16(Bg + 32*KD + (kk),    Bs + (bb)*16384 + 8192  + tid*8); \
                            glds16(Bg + 48*KD + (kk),    Bs + (bb)*16384 + 12288 + tid*8); }

#define RDA(a_, half) { _Pragma("unroll") \
    for (int m = 0; m < 4; m++) { \
        af[m][0] = lds8((a_) + (half)*8192 + arow + m*2048 + psg0); \
        af[m][1] = lds8((a_) + (half)*8192 + arow + m*2048 + psg1); } }
#define RDBP(b_) { _Pragma("unroll") \
    for (int n = 0; n < 2; n++) { \
        bfP[n][0] = lds8((b_) + brow + n*4096 + psg0); \
        bfP[n][1] = lds8((b_) + brow + n*4096 + psg1); } }
#define RDBQ(b_) { _Pragma("unroll") \
    for (int n = 0; n < 2; n++) { \
        bfQ[n][0] = lds8((b_) + brow + (2+n)*4096 + psg0); \
        bfQ[n][1] = lds8((b_) + brow + (2+n)*4096 + psg1); } }

#define MM(mb, nb, BF) { \
    __builtin_amdgcn_s_setprio(1); \
    _Pragma("unroll") \
    for (int m = 0; m < 4; m++) \
        _Pragma("unroll") \
        for (int n = 0; n < 2; n++) { \
            acc[(mb)+m][(nb)+n] = __builtin_amdgcn_mfma_f32_16x16x32_bf16(af[m][0], BF[n][0], acc[(mb)+m][(nb)+n], 0, 0, 0); \
            acc[(mb)+m][(nb)+n] = __builtin_amdgcn_mfma_f32_16x16x32_bf16(af[m][1], BF[n][1], acc[(mb)+m][(nb)+n], 0, 0, 0); } \
    __builtin_amdgcn_s_setprio(0); }

#define VMC(N)  asm volatile("s_waitcnt vmcnt(" #N ")" ::: "memory");
#define LGK0    asm volatile("s_waitcnt lgkmcnt(0)" ::: "memory");
#define BARR    __builtin_amdgcn_s_barrier();

    bf16x8 af[4][2], bfP[2][2], bfQ[2][2];
    const unsigned short* a0 = As;
    const unsigned short* b0 = Bs;
    const unsigned short* a1 = As + 16384;
    const unsigned short* b1 = Bs + 16384;

    // prologue: t0 -> dbuf0 (4 halves), t1 -> dbuf1 (3 halves; Ah1 at iter0 ph1)
    STAGE_AH0(0, 0) STAGE_BH0(0, 0) STAGE_BH1(0, 0) STAGE_AH1(0, 0)
    STAGE_AH0(1, 64) STAGE_BH0(1, 64) STAGE_BH1(1, 64)
    VMC(6)          // t0 fully landed; t1's 3 halves in flight
    BARR

    for (int J = 0; J < 7; ++J) {
        const int k1 = (2*J + 1) * 64, k2 = (2*J + 2) * 64, k3 = (2*J + 3) * 64;
        // ---- tile 2J in dbuf0 ----
        // ph1: Q00
        RDA(a0, 0) RDBP(b0)
        STAGE_AH1(1, k1)
        BARR LGK0 MM(0, 0, bfP) BARR
        // ph2: Q01
        RDBQ(b0)
        STAGE_AH0(0, k2)
        BARR LGK0 MM(0, 2, bfQ) BARR
        // ph3: Q10
        RDA(a0, 1)
        STAGE_BH0(0, k2)
        BARR LGK0 MM(4, 0, bfP) BARR
        // ph4: Q11
        STAGE_BH1(0, k2)
        BARR MM(4, 2, bfQ) VMC(6) BARR
        // ---- tile 2J+1 in dbuf1 ----
        // ph5: Q00
        RDA(a1, 0) RDBP(b1)
        STAGE_AH1(0, k2)
        BARR LGK0 MM(0, 0, bfP) BARR
        // ph6: Q01
        RDBQ(b1)
        STAGE_AH0(1, k3)
        BARR LGK0 MM(0, 2, bfQ) BARR
        // ph7: Q10
        RDA(a1, 1)
        STAGE_BH0(1, k3)
        BARR LGK0 MM(4, 0, bfP) BARR
        // ph8: Q11
        STAGE_BH1(1, k3)
        BARR MM(4, 2, bfQ) VMC(6) BARR
    }
    // ---- tail: tiles 14 (dbuf0) and 15 (dbuf1) ----
    {
        // ph1
        RDA(a0, 0) RDBP(b0)
        STAGE_AH1(1, 15 * 64)
        BARR LGK0 MM(0, 0, bfP) BARR
        // ph2
        RDBQ(b0)
        BARR LGK0 MM(0, 2, bfQ) BARR
        // ph3
        RDA(a0, 1)
        BARR LGK0 MM(4, 0, bfP) BARR
        // ph4
        BARR MM(4, 2, bfQ) VMC(4) BARR
        // ph5
        RDA(a1, 0) RDBP(b1)
        BARR LGK0 MM(0, 0, bfP) VMC(2) BARR
        // ph6
        RDBQ(b1)
        BARR LGK0 MM(0, 2, bfQ) VMC(0) BARR
        // ph7
        RDA(a1, 1)
        BARR LGK0 MM(4, 0, bfP) BARR
        // ph8
        MM(4, 2, bfQ)
    }
#undef STAGE_AH0
#undef STAGE_AH1
#undef STAGE_BH0
#undef STAGE_BH1
#undef RDA
#undef RDBP
#undef RDBQ
#undef MM
#undef VMC
#undef LGK0
#undef BARR

    // epilogue: C/D layout col=lane&15, row=(lane>>4)*4+reg.
    // row map: mBase + (m>>2)*128 + (m&3)*32 + wm*16 + kslot*4 + i
    // col map: cBase + wn*64 + n*16 + rl  (n-inner -> 128B contiguous/wave)
    float bv[4];
    #pragma unroll
    for (int n = 0; n < 4; n++) bv[n] = bias[cBase + wn * 64 + n * 16 + rl];
    #pragma unroll
    for (int m = 0; m < 8; m++) {
        #pragma unroll
        for (int i = 0; i < 4; i++) {
            const size_t row = mBase + (m >> 2) * 128 + (m & 3) * 32 + wm * 16 + kslot * 4 + i;
            #pragma unroll
            for (int n = 0; n < 4; n++) {
                const int col = cBase + wn * 64 + n * 16 + rl;
                const float val = acc[m][n][i] + bv[n];
                if (OUT_BF16) ((unsigned short*)Cp)[row * Nn + col] = f2b(val);
                else          ((float*)Cp)[row * Nn + col] = val;
            }
        }
    }
}

// Per-token head-attention. One wave per token, 4 tokens/block.
__global__ __launch_bounds__(256) void attn_kernel(const unsigned short* __restrict__ qkv,
                                                   unsigned short* __restrict__ outp)
{
    __shared__ __align__(16) unsigned short qs[4][48 * 72];
    __shared__ float ps[4][16 * 17];
    const int tid = threadIdx.x, w = tid >> 6, lane = tid & 63;
    const int t = blockIdx.x * 4 + w;

    const unsigned short* src = qkv + (size_t)t * NQKV;
    #pragma unroll
    for (int i = 0; i < 6; i++) {
        const int e = i * 512 + lane * 8;
        uint4 v = *(const uint4*)(src + e);
        *(uint4*)&qs[w][(e >> 6) * 72 + (e & 63)] = v;
    }
    __syncthreads();

    const int h = lane & 15, g0 = lane >> 4;
    uint4 qv[8];
    #pragma unroll
    for (int i = 0; i < 8; i++) qv[i] = *(const uint4*)&qs[w][h * 72 + i * 8];
    float s[4];
    #pragma unroll
    for (int i = 0; i < 4; i++) {
        const int g = g0 * 4 + i;
        float a = 0.f;
        #pragma unroll
        for (int c = 0; c < 8; c++) {
            uint4 kv = *(const uint4*)&qs[w][(16 + g) * 72 + c * 8];
            uint qa[4] = {qv[c].x, qv[c].y, qv[c].z, qv[c].w};
            uint ka[4] = {kv.x, kv.y, kv.z, kv.w};
            #pragma unroll
            for (int uu = 0; uu < 4; uu++) {
                a += b2f((unsigned short)qa[uu]) * b2f((unsigned short)ka[uu]);
                a += b2f((unsigned short)(qa[uu] >> 16)) * b2f((unsigned short)(ka[uu] >> 16));
            }
        }
        s[i] = a * ATT_SCALE;
    }
    float mx = fmaxf(fmaxf(s[0], s[1]), fmaxf(s[2], s[3]));
    mx = fmaxf(mx, __shfl_xor(mx, 16, 64));
    mx = fmaxf(mx, __shfl_xor(mx, 32, 64));
    float p[4], smv = 0.f;
    #pragma unroll
    for (int i = 0; i < 4; i++) { p[i] = __expf(s[i] - mx); smv += p[i]; }
    smv += __shfl_xor(smv, 16, 64);
    smv += __shfl_xor(smv, 32, 64);
    const float inv = 1.f / smv;
    #pragma unroll
    for (int i = 0; i < 4; i++) ps[w][h * 17 + g0 * 4 + i] = p[i] * inv;
    __syncthreads();

    const int h2 = lane >> 2, db = (lane & 3) * 16;
    float pr[16];
    #pragma unroll
    for (int g = 0; g < 16; g++) pr[g] = ps[w][h2 * 17 + g];
    float acc[16];
    #pragma unroll
    for (int j = 0; j < 16; j++) acc[j] = 0.f;
    #pragma unroll
    for (int g = 0; g < 16; g++) {
        const unsigned short* vp = &qs[w][(32 + g) * 72 + db];
        uint4 v0 = *(const uint4*)vp;
        uint4 v1 = *(const uint4*)(vp + 8);
        const float pg = pr[g];
        uint va[8] = {v0.x, v0.y, v0.z, v0.w, v1.x, v1.y, v1.z, v1.w};
        #pragma unroll
        for (int uu = 0; uu < 8; uu++) {
            acc[2*uu]   += pg * b2f((unsigned short)va[uu]);
            acc[2*uu+1] += pg * b2f((unsigned short)(va[uu] >> 16));
        }
    }
    const int b = t >> 12, n = t & 4095;
    const int n1 = h2 * 256 + (n >> 4);
    const int c0 = (n & 15) * 64 + db;
    union { unsigned short u[16]; uint4 v[2]; } st;
    #pragma unroll
    for (int j = 0; j < 16; j++) st.u[j] = f2b(acc[j]);
    unsigned short* dst = outp + ((size_t)(b * SEQL + n1)) * 1024 + c0;
    *(uint4*)dst       = st.v[0];
    *(uint4*)(dst + 8) = st.v[1];
}

extern "C" void kernel_launch(void* const* d_in, const int* in_sizes, int n_in,
                              void* d_out, int out_size, void* d_ws, size_t ws_size,
                              hipStream_t stream)
{
    const float* x      = (const float*)d_in[0];
    const float* qkv_w  = (const float*)d_in[1];
    const float* qkv_b  = (const float*)d_in[2];
    const float* proj_w = (const float*)d_in[3];
    const float* proj_b = (const float*)d_in[4];

    unsigned short* xb  = (unsigned short*)d_ws;            // 33.5 MB
    unsigned short* qkv = xb + (size_t)TOK * KD;            // 100.7 MB
    unsigned short* qwb = qkv + (size_t)TOK * NQKV;         // 6.3 MB
    unsigned short* pwb = qwb + (size_t)NQKV * KD;          // 2.1 MB
    unsigned short* att = xb;                               // alias (after QKV GEMM)

    hipFuncSetAttribute(reinterpret_cast<const void*>(&gemm256<true>),
                        hipFuncAttributeMaxDynamicSharedMemorySize, 131072);
    hipFuncSetAttribute(reinterpret_cast<const void*>(&gemm256<false>),
                        hipFuncAttributeMaxDynamicSharedMemorySize, 131072);

    cvt_kernel<<<dim3(TOK * KD / 2048), dim3(256), 0, stream>>>(x, xb, TOK * KD);
    cvt_kernel<<<dim3(NQKV * KD / 2048), dim3(256), 0, stream>>>(qkv_w, qwb, NQKV * KD);
    cvt_kernel<<<dim3(KD * KD / 2048), dim3(256), 0, stream>>>(proj_w, pwb, KD * KD);

    gemm256<true><<<dim3(NQKV / 256, TOK / 256), dim3(512), 131072, stream>>>(
        xb, qwb, qkv_b, qkv, NQKV);
    attn_kernel<<<dim3(TOK / 4), dim3(256), 0, stream>>>(qkv, att);
    gemm256<false><<<dim3(KD / 256, TOK / 256), dim3(512), 131072, stream>>>(
        att, pwb, proj_b, (float*)d_out, KD);
}

// Round 9
// 213.248 us; speedup vs baseline: 1.1393x; 1.1393x over previous
//
#include <hip/hip_runtime.h>
#include <hip/hip_bf16.h>

#define TOK   16384       // B*N = 4*4096
#define KD    1024        // DIM
#define NQKV  3072
#define SEQL  4096
#define ATT_SCALE 0.125f  // 64^-0.5

typedef __attribute__((ext_vector_type(16))) float f32x16;
typedef __attribute__((ext_vector_type(8))) short bf16x8;

__device__ __forceinline__ unsigned short f2b(float f){
    union { float f; unsigned u; } x; x.f = f;
    return (unsigned short)((x.u + 0x7FFFu + ((x.u >> 16) & 1u)) >> 16);
}
__device__ __forceinline__ float b2f(unsigned short s){
    union { unsigned u; float f; } x; x.u = ((unsigned)s) << 16;
    return x.f;
}
__device__ __forceinline__ bf16x8 lds8(const unsigned short* p){
    union { uint4 u; bf16x8 v; } t; t.u = *(const uint4*)p; return t.v;
}
__device__ __forceinline__ void glds16(const void* g, void* l){
    __builtin_amdgcn_global_load_lds((const __attribute__((address_space(1))) unsigned*)g,
                                     (__attribute__((address_space(3))) unsigned*)l, 16, 0, 0);
}

// fp32 -> bf16 convert, 8 elems/thread
__global__ __launch_bounds__(256) void cvt_kernel(const float* __restrict__ in,
                                                  unsigned short* __restrict__ out, int n)
{
    int i = (blockIdx.x * 256 + threadIdx.x) * 8;
    if (i >= n) return;
    float4 a = *(const float4*)(in + i);
    float4 b = *(const float4*)(in + i + 4);
    union { unsigned short u[8]; uint4 v; } t;
    t.u[0]=f2b(a.x); t.u[1]=f2b(a.y); t.u[2]=f2b(a.z); t.u[3]=f2b(a.w);
    t.u[4]=f2b(b.x); t.u[5]=f2b(b.y); t.u[6]=f2b(b.z); t.u[7]=f2b(b.w);
    *(uint4*)(out + i) = t.v;
}

// ===== 256x256 GEMM, BK=64, r6 counted-vmcnt(6) schedule, 32x32x16 MFMA =====
// Per-wave out 128x64 = 4 m-frags x 2 n-frags of 32x32, acc 8 x f32x16.
// Fragment maps (k = (lane>>5)*8 + 0..7 per 16-k chunk, mirroring verified 16x16):
//   A (half mh, frag fa, ks): LDS row = mh*128 + wm*64 + fa*32 + (l&31)
//   B (half nh, ks):          LDS row = nh*128 + wn*32 + (l&31)
//   seg(16B) = (2*ks + (l>>5)) ^ (l&7)   [XOR-swizzle, conflict-free]
// B staging permutation: LDS row r holds global col ((r&127)>>5)*64 + (r>>7)*32 + (r&31).
template<bool OUT_BF16>
__global__ __launch_bounds__(512, 2) void gemm256(const unsigned short* __restrict__ A,
        const unsigned short* __restrict__ Bw, const float* __restrict__ bias,
        void* __restrict__ Cp, int Nn)
{
    extern __shared__ unsigned short smem[];
    unsigned short* As = smem;            // [2][256][64] shorts
    unsigned short* Bs = smem + 32768;

    const int tid = threadIdx.x, lane = tid & 63;
    const int w = tid >> 6, wm = w >> 2, wn = w & 3;
    const int l31 = lane & 31, lh = lane >> 5, lx = lane & 7;

    // T1: bijective XCD swizzle (nwg % 8 == 0 for both GEMMs)
    const int gx = gridDim.x;
    const int nwg = gx * gridDim.y;
    int id = blockIdx.y * gx + blockIdx.x;
    id = (id & 7) * (nwg >> 3) + (id >> 3);
    const int cBase = (id % gx) * 256;
    const int mBase = (id / gx) * 256;

    // staging: thread covers LDS row u (per 64-row chunk), seg tid&7;
    // global source seg pre-swizzled with (LDS row)&7 = u&7.
    const int u = tid >> 3;
    const int seg8 = ((tid & 7) ^ (u & 7)) * 8;
    const unsigned short* Ag = A + (size_t)(mBase + u) * KD + seg8;
    // B: LDS row u <-> global col colmap(u) = ((u&127)>>5)*64 + (u>>7)*32 + (u&31)
    const int bcol = ((u & 127) >> 5) * 64 + (u >> 7) * 32 + (u & 31);
    const unsigned short* Bg = Bw + (size_t)(cBase + bcol) * KD + seg8;

    // fragment read offsets (shorts)
    const int arowbase = (wm * 64 + l31) * 64;   // + mh*8192 + fa*2048
    const int bbase    = (wn * 32 + l31) * 64;   // + nh*8192
    int sgk[4];
    #pragma unroll
    for (int ks = 0; ks < 4; ks++) sgk[ks] = ((2 * ks + lh) ^ lx) * 8;

    f32x16 acc[4][2];
    #pragma unroll
    for (int mf = 0; mf < 4; mf++)
        #pragma unroll
        for (int nf = 0; nf < 2; nf++) acc[mf][nf] = (f32x16)0.f;

    // chunk offsets: A rows identity; B chunks (64 LDS rows): H0 {0,+128K}, H1 {+32K,+160K}
#define STAGE_AH0(bb, kk) { glds16(Ag + (kk),            As + (bb)*16384 + tid*8); \
                            glds16(Ag + 64*KD + (kk),    As + (bb)*16384 + 4096  + tid*8); }
#define STAGE_AH1(bb, kk) { glds16(Ag + 128*KD + (kk),   As + (bb)*16384 + 8192  + tid*8); \
                            glds16(Ag + 192*KD + (kk),   As + (bb)*16384 + 12288 + tid*8); }
#define STAGE_BH0(bb, kk) { glds16(Bg + (kk),            Bs + (bb)*16384 + tid*8); \
                            glds16(Bg + 128*KD + (kk),   Bs + (bb)*16384 + 4096  + tid*8); }
#define STAGE_BH1(bb, kk) { glds16(Bg + 32*KD + (kk),    Bs + (bb)*16384 + 8192  + tid*8); \
                            glds16(Bg + 160*KD + (kk),   Bs + (bb)*16384 + 12288 + tid*8); }

#define RDA(a_, mh) { _Pragma("unroll") \
    for (int fa = 0; fa < 2; fa++) \
        _Pragma("unroll") \
        for (int ks = 0; ks < 4; ks++) \
            af[fa][ks] = lds8((a_) + (mh)*8192 + arowbase + fa*2048 + sgk[ks]); }
#define RDB(b_, nh, BF) { _Pragma("unroll") \
    for (int ks = 0; ks < 4; ks++) \
        BF[ks] = lds8((b_) + (nh)*8192 + bbase + sgk[ks]); }

#define MM(mh, nh, BF) { \
    __builtin_amdgcn_s_setprio(1); \
    _Pragma("unroll") \
    for (int ks = 0; ks < 4; ks++) \
        _Pragma("unroll") \
        for (int fa = 0; fa < 2; fa++) \
            acc[(mh)*2+fa][nh] = __builtin_amdgcn_mfma_f32_32x32x16_bf16(af[fa][ks], BF[ks], acc[(mh)*2+fa][nh], 0, 0, 0); \
    __builtin_amdgcn_s_setprio(0); }

#define VMC(N)  asm volatile("s_waitcnt vmcnt(" #N ")" ::: "memory");
#define BARR    __builtin_amdgcn_s_barrier();

    bf16x8 af[2][4], bfP[4], bfQ[4];

    // prologue: tile 0 -> buf 0 (8 loads)
    STAGE_AH0(0, 0)
    STAGE_BH0(0, 0)
    STAGE_BH1(0, 0)
    STAGE_AH1(0, 0)

    int buf = 0;
    for (int t = 0; t < 15; ++t) {
        const unsigned short* a = As + buf * 16384;
        const unsigned short* b = Bs + buf * 16384;
        const int nk = (t + 1) * 64;
        // P0: needs Ah0(t), Bh0(t)
        STAGE_AH0(buf ^ 1, nk)
        VMC(6)
        BARR
        RDA(a, 0) RDB(b, 0, bfP)
        MM(0, 0, bfP)
        // P1: needs Bh1(t)
        STAGE_BH0(buf ^ 1, nk)
        VMC(6)
        BARR
        RDB(b, 1, bfQ)
        MM(0, 1, bfQ)
        // P2: needs Ah1(t)
        STAGE_BH1(buf ^ 1, nk)
        VMC(6)
        BARR
        RDA(a, 1)
        MM(1, 0, bfP)
        // P3: register-only
        STAGE_AH1(buf ^ 1, nk)
        MM(1, 1, bfQ)
        buf ^= 1;
    }
    // tail tile 15 (no staging; counted drain 4 -> 2 -> 0)
    {
        const unsigned short* a = As + buf * 16384;
        const unsigned short* b = Bs + buf * 16384;
        VMC(4)
        BARR
        RDA(a, 0) RDB(b, 0, bfP)
        MM(0, 0, bfP)
        VMC(2)
        BARR
        RDB(b, 1, bfQ)
        MM(0, 1, bfQ)
        VMC(0)
        BARR
        RDA(a, 1)
        MM(1, 0, bfP)
        MM(1, 1, bfQ)
    }
#undef STAGE_AH0
#undef STAGE_AH1
#undef STAGE_BH0
#undef STAGE_BH1
#undef RDA
#undef RDB
#undef MM
#undef VMC
#undef BARR

    // epilogue: 32x32 C/D layout col=lane&31, row=(reg&3)+8*(reg>>2)+4*(lane>>5)
    // row = mBase + (mf>>1)*128 + wm*64 + (mf&1)*32 + lh*4 + (reg&3) + 8*(reg>>2)
    // col = cBase + wn*64 + nf*32 + l31   (nf-inner -> 128B contiguous per row)
    float bv[2];
    #pragma unroll
    for (int nf = 0; nf < 2; nf++) bv[nf] = bias[cBase + wn * 64 + nf * 32 + l31];
    #pragma unroll
    for (int mf = 0; mf < 4; mf++) {
        const int row0 = mBase + (mf >> 1) * 128 + wm * 64 + (mf & 1) * 32 + lh * 4;
        #pragma unroll
        for (int reg = 0; reg < 16; reg++) {
            const size_t row = row0 + (reg & 3) + 8 * (reg >> 2);
            #pragma unroll
            for (int nf = 0; nf < 2; nf++) {
                const int col = cBase + wn * 64 + nf * 32 + l31;
                const float val = acc[mf][nf][reg] + bv[nf];
                if (OUT_BF16) ((unsigned short*)Cp)[row * Nn + col] = f2b(val);
                else          ((float*)Cp)[row * Nn + col] = val;
            }
        }
    }
}

// Per-token head-attention. One wave per token, 4 tokens/block.
__global__ __launch_bounds__(256) void attn_kernel(const unsigned short* __restrict__ qkv,
                                                   unsigned short* __restrict__ outp)
{
    __shared__ __align__(16) unsigned short qs[4][48 * 72];
    __shared__ float ps[4][16 * 17];
    const int tid = threadIdx.x, w = tid >> 6, lane = tid & 63;
    const int t = blockIdx.x * 4 + w;

    const unsigned short* src = qkv + (size_t)t * NQKV;
    #pragma unroll
    for (int i = 0; i < 6; i++) {
        const int e = i * 512 + lane * 8;
        uint4 v = *(const uint4*)(src + e);
        *(uint4*)&qs[w][(e >> 6) * 72 + (e & 63)] = v;
    }
    __syncthreads();

    const int h = lane & 15, g0 = lane >> 4;
    uint4 qv[8];
    #pragma unroll
    for (int i = 0; i < 8; i++) qv[i] = *(const uint4*)&qs[w][h * 72 + i * 8];
    float s[4];
    #pragma unroll
    for (int i = 0; i < 4; i++) {
        const int g = g0 * 4 + i;
        float a = 0.f;
        #pragma unroll
        for (int c = 0; c < 8; c++) {
            uint4 kv = *(const uint4*)&qs[w][(16 + g) * 72 + c * 8];
            uint qa[4] = {qv[c].x, qv[c].y, qv[c].z, qv[c].w};
            uint ka[4] = {kv.x, kv.y, kv.z, kv.w};
            #pragma unroll
            for (int uu = 0; uu < 4; uu++) {
                a += b2f((unsigned short)qa[uu]) * b2f((unsigned short)ka[uu]);
                a += b2f((unsigned short)(qa[uu] >> 16)) * b2f((unsigned short)(ka[uu] >> 16));
            }
        }
        s[i] = a * ATT_SCALE;
    }
    float mx = fmaxf(fmaxf(s[0], s[1]), fmaxf(s[2], s[3]));
    mx = fmaxf(mx, __shfl_xor(mx, 16, 64));
    mx = fmaxf(mx, __shfl_xor(mx, 32, 64));
    float p[4], smv = 0.f;
    #pragma unroll
    for (int i = 0; i < 4; i++) { p[i] = __expf(s[i] - mx); smv += p[i]; }
    smv += __shfl_xor(smv, 16, 64);
    smv += __shfl_xor(smv, 32, 64);
    const float inv = 1.f / smv;
    #pragma unroll
    for (int i = 0; i < 4; i++) ps[w][h * 17 + g0 * 4 + i] = p[i] * inv;
    __syncthreads();

    const int h2 = lane >> 2, db = (lane & 3) * 16;
    float pr[16];
    #pragma unroll
    for (int g = 0; g < 16; g++) pr[g] = ps[w][h2 * 17 + g];
    float acc[16];
    #pragma unroll
    for (int j = 0; j < 16; j++) acc[j] = 0.f;
    #pragma unroll
    for (int g = 0; g < 16; g++) {
        const unsigned short* vp = &qs[w][(32 + g) * 72 + db];
        uint4 v0 = *(const uint4*)vp;
        uint4 v1 = *(const uint4*)(vp + 8);
        const float pg = pr[g];
        uint va[8] = {v0.x, v0.y, v0.z, v0.w, v1.x, v1.y, v1.z, v1.w};
        #pragma unroll
        for (int uu = 0; uu < 8; uu++) {
            acc[2*uu]   += pg * b2f((unsigned short)va[uu]);
            acc[2*uu+1] += pg * b2f((unsigned short)(va[uu] >> 16));
        }
    }
    const int b = t >> 12, n = t & 4095;
    const int n1 = h2 * 256 + (n >> 4);
    const int c0 = (n & 15) * 64 + db;
    union { unsigned short u[16]; uint4 v[2]; } st;
    #pragma unroll
    for (int j = 0; j < 16; j++) st.u[j] = f2b(acc[j]);
    unsigned short* dst = outp + ((size_t)(b * SEQL + n1)) * 1024 + c0;
    *(uint4*)dst       = st.v[0];
    *(uint4*)(dst + 8) = st.v[1];
}

extern "C" void kernel_launch(void* const* d_in, const int* in_sizes, int n_in,
                              void* d_out, int out_size, void* d_ws, size_t ws_size,
                              hipStream_t stream)
{
    const float* x      = (const float*)d_in[0];
    const float* qkv_w  = (const float*)d_in[1];
    const float* qkv_b  = (const float*)d_in[2];
    const float* proj_w = (const float*)d_in[3];
    const float* proj_b = (const float*)d_in[4];

    unsigned short* xb  = (unsigned short*)d_ws;            // 33.5 MB
    unsigned short* qkv = xb + (size_t)TOK * KD;            // 100.7 MB
    unsigned short* qwb = qkv + (size_t)TOK * NQKV;         // 6.3 MB
    unsigned short* pwb = qwb + (size_t)NQKV * KD;          // 2.1 MB
    unsigned short* att = xb;                               // alias (after QKV GEMM)

    hipFuncSetAttribute(reinterpret_cast<const void*>(&gemm256<true>),
                        hipFuncAttributeMaxDynamicSharedMemorySize, 131072);
    hipFuncSetAttribute(reinterpret_cast<const void*>(&gemm256<false>),
                        hipFuncAttributeMaxDynamicSharedMemorySize, 131072);

    cvt_kernel<<<dim3(TOK * KD / 2048), dim3(256), 0, stream>>>(x, xb, TOK * KD);
    cvt_kernel<<<dim3(NQKV * KD / 2048), dim3(256), 0, stream>>>(qkv_w, qwb, NQKV * KD);
    cvt_kernel<<<dim3(KD * KD / 2048), dim3(256), 0, stream>>>(proj_w, pwb, KD * KD);

    gemm256<true><<<dim3(NQKV / 256, TOK / 256), dim3(512), 131072, stream>>>(
        xb, qwb, qkv_b, qkv, NQKV);
    attn_kernel<<<dim3(TOK / 4), dim3(256), 0, stream>>>(qkv, att);
    gemm256<false><<<dim3(KD / 256, TOK / 256), dim3(512), 131072, stream>>>(
        att, pwb, proj_b, (float*)d_out, KD);
}

// Round 10
// 208.098 us; speedup vs baseline: 1.1675x; 1.0247x over previous
//
#include <hip/hip_runtime.h>
#include <hip/hip_bf16.h>

#define TOK   16384       // B*N = 4*4096
#define KD    1024        // DIM
#define NQKV  3072
#define SEQL  4096
#define ATT_SCALE 0.125f  // 64^-0.5

typedef __attribute__((ext_vector_type(4))) float f32x4;
typedef __attribute__((ext_vector_type(8))) short bf16x8;

__device__ __forceinline__ unsigned short f2b(float f){
    union { float f; unsigned u; } x; x.f = f;
    return (unsigned short)((x.u + 0x7FFFu + ((x.u >> 16) & 1u)) >> 16);
}
__device__ __forceinline__ float b2f(unsigned short s){
    union { unsigned u; float f; } x; x.u = ((unsigned)s) << 16;
    return x.f;
}
__device__ __forceinline__ bf16x8 lds8(const unsigned short* p){
    union { uint4 u; bf16x8 v; } t; t.u = *(const uint4*)p; return t.v;
}
__device__ __forceinline__ void glds16(const void* g, void* l){
    __builtin_amdgcn_global_load_lds((const __attribute__((address_space(1))) unsigned*)g,
                                     (__attribute__((address_space(3))) unsigned*)l, 16, 0, 0);
}

// merged fp32 -> bf16 convert for x (8192 blks), qkv_w (1536), proj_w (512)
__global__ __launch_bounds__(256) void cvt3_kernel(const float* __restrict__ x,
        const float* __restrict__ qw, const float* __restrict__ pw,
        unsigned short* __restrict__ xb, unsigned short* __restrict__ qwb,
        unsigned short* __restrict__ pwb)
{
    const int b = blockIdx.x;
    const float* src; unsigned short* dst; int off;
    if (b < 8192)       { src = x;  dst = xb;  off = b; }
    else if (b < 9728)  { src = qw; dst = qwb; off = b - 8192; }
    else                { src = pw; dst = pwb; off = b - 9728; }
    const int i = (off * 256 + threadIdx.x) * 8;
    float4 a = *(const float4*)(src + i);
    float4 c = *(const float4*)(src + i + 4);
    union { unsigned short u[8]; uint4 v; } t;
    t.u[0]=f2b(a.x); t.u[1]=f2b(a.y); t.u[2]=f2b(a.z); t.u[3]=f2b(a.w);
    t.u[4]=f2b(c.x); t.u[5]=f2b(c.y); t.u[6]=f2b(c.z); t.u[7]=f2b(c.w);
    *(uint4*)(dst + i) = t.v;
}

// ===== 256x256 GEMM (r6, best measured): BK=64, quadrant phases, vmcnt(6) =====
template<bool OUT_BF16>
__global__ __launch_bounds__(512, 2) void gemm256(const unsigned short* __restrict__ A,
        const unsigned short* __restrict__ Bw, const float* __restrict__ bias,
        void* __restrict__ Cp, int Nn)
{
    extern __shared__ unsigned short smem[];
    unsigned short* As = smem;            // [2][256][64] shorts
    unsigned short* Bs = smem + 32768;

    const int tid = threadIdx.x, lane = tid & 63;
    const int w = tid >> 6, wm = w >> 2, wn = w & 3;
    const int rl = lane & 15, kslot = lane >> 4;

    const int gx = gridDim.x;
    const int nwg = gx * gridDim.y;
    int id = blockIdx.y * gx + blockIdx.x;
    id = (id & 7) * (nwg >> 3) + (id >> 3);
    const int cBase = (id % gx) * 256;
    const int mBase = (id / gx) * 256;

    const int u = tid >> 3;
    const int seg8 = ((tid & 7) ^ (u & 7)) * 8;
    const unsigned short* Ag = A  + (size_t)(mBase + u) * KD + seg8;
    const unsigned short* Bg = Bw + (size_t)(cBase + (u >> 4) * 64 + (u & 15)) * KD + seg8;

    const int arow = (wm * 16 + rl) * 64;
    const int brow = (wn * 16 + rl) * 64;
    const int psg0 = (kslot ^ (rl & 7)) * 8;
    const int psg1 = ((kslot + 4) ^ (rl & 7)) * 8;

    f32x4 acc[8][4];
    #pragma unroll
    for (int m = 0; m < 8; m++)
        #pragma unroll
        for (int n = 0; n < 4; n++) acc[m][n] = (f32x4)0.f;

#define STAGE_AH0(bb, kk) { glds16(Ag + (kk),            As + (bb)*16384 + tid*8); \
                            glds16(Ag + 64*KD + (kk),    As + (bb)*16384 + 4096  + tid*8); }
#define STAGE_AH1(bb, kk) { glds16(Ag + 128*KD + (kk),   As + (bb)*16384 + 8192  + tid*8); \
                            glds16(Ag + 192*KD + (kk),   As + (bb)*16384 + 12288 + tid*8); }
#define STAGE_BH0(bb, kk) { glds16(Bg + (kk),            Bs + (bb)*16384 + tid*8); \
                            glds16(Bg + 16*KD + (kk),    Bs + (bb)*16384 + 4096  + tid*8); }
#define STAGE_BH1(bb, kk) { glds16(Bg + 32*KD + (kk),    Bs + (bb)*16384 + 8192  + tid*8); \
                            glds16(Bg + 48*KD + (kk),    Bs + (bb)*16384 + 12288 + tid*8); }

#define RDA(a_, half) { _Pragma("unroll") \
    for (int m = 0; m < 4; m++) { \
        af[m][0] = lds8((a_) + (half)*8192 + arow + m*2048 + psg0); \
        af[m][1] = lds8((a_) + (half)*8192 + arow + m*2048 + psg1); } }
#define RDB(b_, nlo, BF) { _Pragma("unroll") \
    for (int n = 0; n < 2; n++) { \
        BF[n][0] = lds8((b_) + brow + ((nlo)+n)*4096 + psg0); \
        BF[n][1] = lds8((b_) + brow + ((nlo)+n)*4096 + psg1); } }

#define MM16(mb, nb, BF) { \
    __builtin_amdgcn_s_setprio(1); \
    _Pragma("unroll") \
    for (int m = 0; m < 4; m++) \
        _Pragma("unroll") \
        for (int n = 0; n < 2; n++) { \
            acc[(mb)+m][(nb)+n] = __builtin_amdgcn_mfma_f32_16x16x32_bf16(af[m][0], BF[n][0], acc[(mb)+m][(nb)+n], 0, 0, 0); \
            acc[(mb)+m][(nb)+n] = __builtin_amdgcn_mfma_f32_16x16x32_bf16(af[m][1], BF[n][1], acc[(mb)+m][(nb)+n], 0, 0, 0); } \
    __builtin_amdgcn_s_setprio(0); }

#define VMC(N)  asm volatile("s_waitcnt vmcnt(" #N ")" ::: "memory");
#define BARR    __builtin_amdgcn_s_barrier();

    bf16x8 af[4][2], bfP[2][2], bfQ[2][2];

    STAGE_AH0(0, 0)
    STAGE_BH0(0, 0)
    STAGE_BH1(0, 0)
    STAGE_AH1(0, 0)

    int buf = 0;
    for (int t = 0; t < 15; ++t) {
        const unsigned short* a = As + buf * 16384;
        const unsigned short* b = Bs + buf * 16384;
        const int nk = (t + 1) * 64;
        STAGE_AH0(buf ^ 1, nk)
        VMC(6)
        BARR
        RDA(a, 0) RDB(b, 0, bfP)
        MM16(0, 0, bfP)
        STAGE_BH0(buf ^ 1, nk)
        VMC(6)
        BARR
        RDB(b, 2, bfQ)
        MM16(0, 2, bfQ)
        STAGE_BH1(buf ^ 1, nk)
        VMC(6)
        BARR
        RDA(a, 1)
        MM16(4, 0, bfP)
        STAGE_AH1(buf ^ 1, nk)
        MM16(4, 2, bfQ)
        buf ^= 1;
    }
    {
        const unsigned short* a = As + buf * 16384;
        const unsigned short* b = Bs + buf * 16384;
        VMC(4)
        BARR
        RDA(a, 0) RDB(b, 0, bfP)
        MM16(0, 0, bfP)
        VMC(2)
        BARR
        RDB(b, 2, bfQ)
        MM16(0, 2, bfQ)
        VMC(0)
        BARR
        RDA(a, 1)
        MM16(4, 0, bfP)
        MM16(4, 2, bfQ)
    }
#undef STAGE_AH0
#undef STAGE_AH1
#undef STAGE_BH0
#undef STAGE_BH1
#undef RDA
#undef RDB
#undef MM16
#undef VMC
#undef BARR

    float bv[4];
    #pragma unroll
    for (int n = 0; n < 4; n++) bv[n] = bias[cBase + wn * 64 + n * 16 + rl];
    #pragma unroll
    for (int m = 0; m < 8; m++) {
        #pragma unroll
        for (int i = 0; i < 4; i++) {
            const size_t row = mBase + (m >> 2) * 128 + (m & 3) * 32 + wm * 16 + kslot * 4 + i;
            #pragma unroll
            for (int n = 0; n < 4; n++) {
                const int col = cBase + wn * 64 + n * 16 + rl;
                const float val = acc[m][n][i] + bv[n];
                if (OUT_BF16) ((unsigned short*)Cp)[row * Nn + col] = f2b(val);
                else          ((float*)Cp)[row * Nn + col] = val;
            }
        }
    }
}

// ===== 128x128 GEMM: 4 waves (2x2), BK=64, 64KiB dbuf -> 2 blocks/CU =====
// Same counted-vmcnt(6) quadrant schedule as gemm256, halved.
// A-frag m row = (m>>1)*64 + wm*32 + (m&1)*16 + rl  (half = m>>1)
// B LDS row r holds global col ((r>>5)&1)*64 + (((r>>6)&1)*2+((r>>4)&1))*16 + (r&15)
template<bool OUT_BF16>
__global__ __launch_bounds__(256, 2) void gemm128(const unsigned short* __restrict__ A,
        const unsigned short* __restrict__ Bw, const float* __restrict__ bias,
        void* __restrict__ Cp, int Nn)
{
    extern __shared__ unsigned short smem[];
    unsigned short* As = smem;            // [2][128][64] shorts
    unsigned short* Bs = smem + 16384;

    const int tid = threadIdx.x, lane = tid & 63;
    const int w = tid >> 6, wm = w >> 1, wn = w & 1;
    const int rl = lane & 15, kslot = lane >> 4;

    const int gx = gridDim.x;
    const int nwg = gx * gridDim.y;
    int id = blockIdx.y * gx + blockIdx.x;
    id = (id & 7) * (nwg >> 3) + (id >> 3);
    const int cBase = (id % gx) * 128;
    const int mBase = (id / gx) * 128;

    // staging: u = tid>>3 in 0..31; chunk = 32 rows (1 glds / 256 thr)
    const int u = tid >> 3;
    const int seg8 = ((tid & 7) ^ (u & 7)) * 8;
    const unsigned short* Ag = A + (size_t)(mBase + u) * KD + seg8;
    const int bq = ((u >> 4) & 1) * 16 + (u & 15);
    const unsigned short* Bg = Bw + (size_t)(cBase + bq) * KD + seg8;

    const int arow = wm * 2048 + rl * 64;   // + half*4096 + q*1024
    const int brow = wn * 2048 + rl * 64;
    const int psg0 = (kslot ^ (rl & 7)) * 8;
    const int psg1 = ((kslot + 4) ^ (rl & 7)) * 8;

    f32x4 acc[4][4];
    #pragma unroll
    for (int m = 0; m < 4; m++)
        #pragma unroll
        for (int n = 0; n < 4; n++) acc[m][n] = (f32x4)0.f;

    // A chunks: rows identity. B chunks c: cols bq + {0,64,32,96} (colmap-consistent)
#define STAGE_AH0(bb, kk) { glds16(Ag + (kk),           As + (bb)*8192 + tid*8); \
                            glds16(Ag + 32*KD + (kk),   As + (bb)*8192 + 2048 + tid*8); }
#define STAGE_AH1(bb, kk) { glds16(Ag + 64*KD + (kk),   As + (bb)*8192 + 4096 + tid*8); \
                            glds16(Ag + 96*KD + (kk),   As + (bb)*8192 + 6144 + tid*8); }
#define STAGE_BH0(bb, kk) { glds16(Bg + (kk),           Bs + (bb)*8192 + tid*8); \
                            glds16(Bg + 64*KD + (kk),   Bs + (bb)*8192 + 2048 + tid*8); }
#define STAGE_BH1(bb, kk) { glds16(Bg + 32*KD + (kk),   Bs + (bb)*8192 + 4096 + tid*8); \
                            glds16(Bg + 96*KD + (kk),   Bs + (bb)*8192 + 6144 + tid*8); }

#define RDA(a_, half) { _Pragma("unroll") \
    for (int q = 0; q < 2; q++) { \
        af[q][0] = lds8((a_) + (half)*4096 + arow + q*1024 + psg0); \
        af[q][1] = lds8((a_) + (half)*4096 + arow + q*1024 + psg1); } }
#define RDB(b_, half, BF) { _Pragma("unroll") \
    for (int q = 0; q < 2; q++) { \
        BF[q][0] = lds8((b_) + (half)*4096 + brow + q*1024 + psg0); \
        BF[q][1] = lds8((b_) + (half)*4096 + brow + q*1024 + psg1); } }

#define MM8(mh, nh, BF) { \
    __builtin_amdgcn_s_setprio(1); \
    _Pragma("unroll") \
    for (int qa = 0; qa < 2; qa++) \
        _Pragma("unroll") \
        for (int qb = 0; qb < 2; qb++) { \
            acc[(mh)*2+qa][(nh)*2+qb] = __builtin_amdgcn_mfma_f32_16x16x32_bf16(af[qa][0], BF[qb][0], acc[(mh)*2+qa][(nh)*2+qb], 0, 0, 0); \
            acc[(mh)*2+qa][(nh)*2+qb] = __builtin_amdgcn_mfma_f32_16x16x32_bf16(af[qa][1], BF[qb][1], acc[(mh)*2+qa][(nh)*2+qb], 0, 0, 0); } \
    __builtin_amdgcn_s_setprio(0); }

#define VMC(N)  asm volatile("s_waitcnt vmcnt(" #N ")" ::: "memory");
#define BARR    __builtin_amdgcn_s_barrier();

    bf16x8 af[2][2], bfP[2][2], bfQ[2][2];

    STAGE_AH0(0, 0)
    STAGE_BH0(0, 0)
    STAGE_BH1(0, 0)
    STAGE_AH1(0, 0)

    int buf = 0;
    for (int t = 0; t < 15; ++t) {
        const unsigned short* a = As + buf * 8192;
        const unsigned short* b = Bs + buf * 8192;
        const int nk = (t + 1) * 64;
        STAGE_AH0(buf ^ 1, nk)
        VMC(6)
        BARR
        RDA(a, 0) RDB(b, 0, bfP)
        MM8(0, 0, bfP)
        STAGE_BH0(buf ^ 1, nk)
        VMC(6)
        BARR
        RDB(b, 1, bfQ)
        MM8(0, 1, bfQ)
        STAGE_BH1(buf ^ 1, nk)
        VMC(6)
        BARR
        RDA(a, 1)
        MM8(1, 0, bfP)
        STAGE_AH1(buf ^ 1, nk)
        MM8(1, 1, bfQ)
        buf ^= 1;
    }
    {
        const unsigned short* a = As + buf * 8192;
        const unsigned short* b = Bs + buf * 8192;
        VMC(4)
        BARR
        RDA(a, 0) RDB(b, 0, bfP)
        MM8(0, 0, bfP)
        VMC(2)
        BARR
        RDB(b, 1, bfQ)
        MM8(0, 1, bfQ)
        VMC(0)
        BARR
        RDA(a, 1)
        MM8(1, 0, bfP)
        MM8(1, 1, bfQ)
    }
#undef STAGE_AH0
#undef STAGE_AH1
#undef STAGE_BH0
#undef STAGE_BH1
#undef RDA
#undef RDB
#undef MM8
#undef VMC
#undef BARR

    // epilogue: row = mBase + (m>>1)*64 + wm*32 + (m&1)*16 + kslot*4 + i
    //           col = cBase + wn*64 + n*16 + rl
    float bv[4];
    #pragma unroll
    for (int n = 0; n < 4; n++) bv[n] = bias[cBase + wn * 64 + n * 16 + rl];
    #pragma unroll
    for (int m = 0; m < 4; m++) {
        #pragma unroll
        for (int i = 0; i < 4; i++) {
            const size_t row = mBase + (m >> 1) * 64 + wm * 32 + (m & 1) * 16 + kslot * 4 + i;
            #pragma unroll
            for (int n = 0; n < 4; n++) {
                const int col = cBase + wn * 64 + n * 16 + rl;
                const float val = acc[m][n][i] + bv[n];
                if (OUT_BF16) ((unsigned short*)Cp)[row * Nn + col] = f2b(val);
                else          ((float*)Cp)[row * Nn + col] = val;
            }
        }
    }
}

// Per-token head-attention. One wave per token, 4 tokens/block.
__global__ __launch_bounds__(256) void attn_kernel(const unsigned short* __restrict__ qkv,
                                                   unsigned short* __restrict__ outp)
{
    __shared__ __align__(16) unsigned short qs[4][48 * 72];
    __shared__ float ps[4][16 * 17];
    const int tid = threadIdx.x, w = tid >> 6, lane = tid & 63;
    const int t = blockIdx.x * 4 + w;

    const unsigned short* src = qkv + (size_t)t * NQKV;
    #pragma unroll
    for (int i = 0; i < 6; i++) {
        const int e = i * 512 + lane * 8;
        uint4 v = *(const uint4*)(src + e);
        *(uint4*)&qs[w][(e >> 6) * 72 + (e & 63)] = v;
    }
    __syncthreads();

    const int h = lane & 15, g0 = lane >> 4;
    uint4 qv[8];
    #pragma unroll
    for (int i = 0; i < 8; i++) qv[i] = *(const uint4*)&qs[w][h * 72 + i * 8];
    float s[4];
    #pragma unroll
    for (int i = 0; i < 4; i++) {
        const int g = g0 * 4 + i;
        float a = 0.f;
        #pragma unroll
        for (int c = 0; c < 8; c++) {
            uint4 kv = *(const uint4*)&qs[w][(16 + g) * 72 + c * 8];
            uint qa[4] = {qv[c].x, qv[c].y, qv[c].z, qv[c].w};
            uint ka[4] = {kv.x, kv.y, kv.z, kv.w};
            #pragma unroll
            for (int uu = 0; uu < 4; uu++) {
                a += b2f((unsigned short)qa[uu]) * b2f((unsigned short)ka[uu]);
                a += b2f((unsigned short)(qa[uu] >> 16)) * b2f((unsigned short)(ka[uu] >> 16));
            }
        }
        s[i] = a * ATT_SCALE;
    }
    float mx = fmaxf(fmaxf(s[0], s[1]), fmaxf(s[2], s[3]));
    mx = fmaxf(mx, __shfl_xor(mx, 16, 64));
    mx = fmaxf(mx, __shfl_xor(mx, 32, 64));
    float p[4], smv = 0.f;
    #pragma unroll
    for (int i = 0; i < 4; i++) { p[i] = __expf(s[i] - mx); smv += p[i]; }
    smv += __shfl_xor(smv, 16, 64);
    smv += __shfl_xor(smv, 32, 64);
    const float inv = 1.f / smv;
    #pragma unroll
    for (int i = 0; i < 4; i++) ps[w][h * 17 + g0 * 4 + i] = p[i] * inv;
    __syncthreads();

    const int h2 = lane >> 2, db = (lane & 3) * 16;
    float pr[16];
    #pragma unroll
    for (int g = 0; g < 16; g++) pr[g] = ps[w][h2 * 17 + g];
    float acc[16];
    #pragma unroll
    for (int j = 0; j < 16; j++) acc[j] = 0.f;
    #pragma unroll
    for (int g = 0; g < 16; g++) {
        const unsigned short* vp = &qs[w][(32 + g) * 72 + db];
        uint4 v0 = *(const uint4*)vp;
        uint4 v1 = *(const uint4*)(vp + 8);
        const float pg = pr[g];
        uint va[8] = {v0.x, v0.y, v0.z, v0.w, v1.x, v1.y, v1.z, v1.w};
        #pragma unroll
        for (int uu = 0; uu < 8; uu++) {
            acc[2*uu]   += pg * b2f((unsigned short)va[uu]);
            acc[2*uu+1] += pg * b2f((unsigned short)(va[uu] >> 16));
        }
    }
    const int b = t >> 12, n = t & 4095;
    const int n1 = h2 * 256 + (n >> 4);
    const int c0 = (n & 15) * 64 + db;
    union { unsigned short u[16]; uint4 v[2]; } st;
    #pragma unroll
    for (int j = 0; j < 16; j++) st.u[j] = f2b(acc[j]);
    unsigned short* dst = outp + ((size_t)(b * SEQL + n1)) * 1024 + c0;
    *(uint4*)dst       = st.v[0];
    *(uint4*)(dst + 8) = st.v[1];
}

extern "C" void kernel_launch(void* const* d_in, const int* in_sizes, int n_in,
                              void* d_out, int out_size, void* d_ws, size_t ws_size,
                              hipStream_t stream)
{
    const float* x      = (const float*)d_in[0];
    const float* qkv_w  = (const float*)d_in[1];
    const float* qkv_b  = (const float*)d_in[2];
    const float* proj_w = (const float*)d_in[3];
    const float* proj_b = (const float*)d_in[4];

    unsigned short* xb  = (unsigned short*)d_ws;            // 33.5 MB
    unsigned short* qkv = xb + (size_t)TOK * KD;            // 100.7 MB
    unsigned short* qwb = qkv + (size_t)TOK * NQKV;         // 6.3 MB
    unsigned short* pwb = qwb + (size_t)NQKV * KD;          // 2.1 MB
    unsigned short* att = xb;                               // alias (after QKV GEMM)

    hipFuncSetAttribute(reinterpret_cast<const void*>(&gemm256<true>),
                        hipFuncAttributeMaxDynamicSharedMemorySize, 131072);
    hipFuncSetAttribute(reinterpret_cast<const void*>(&gemm128<false>),
                        hipFuncAttributeMaxDynamicSharedMemorySize, 65536);

    cvt3_kernel<<<dim3(10240), dim3(256), 0, stream>>>(x, qkv_w, proj_w, xb, qwb, pwb);

    gemm256<true><<<dim3(NQKV / 256, TOK / 256), dim3(512), 131072, stream>>>(
        xb, qwb, qkv_b, qkv, NQKV);
    attn_kernel<<<dim3(TOK / 4), dim3(256), 0, stream>>>(qkv, att);
    gemm128<false><<<dim3(KD / 128, TOK / 128), dim3(256), 65536, stream>>>(
        att, pwb, proj_b, (float*)d_out, KD);
}

// Round 11
// 196.712 us; speedup vs baseline: 1.2351x; 1.0579x over previous
//
#include <hip/hip_runtime.h>
#include <hip/hip_bf16.h>

#define TOK   16384       // B*N = 4*4096
#define KD    1024        // DIM
#define NQKV  3072
#define SEQL  4096
#define ATT_SCALE 0.125f  // 64^-0.5

typedef __attribute__((ext_vector_type(4))) float f32x4;
typedef __attribute__((ext_vector_type(8))) short bf16x8;

__device__ __forceinline__ unsigned short f2b(float f){
    union { float f; unsigned u; } x; x.f = f;
    return (unsigned short)((x.u + 0x7FFFu + ((x.u >> 16) & 1u)) >> 16);
}
__device__ __forceinline__ float b2f(unsigned short s){
    union { unsigned u; float f; } x; x.u = ((unsigned)s) << 16;
    return x.f;
}
__device__ __forceinline__ bf16x8 lds8(const unsigned short* p){
    union { uint4 u; bf16x8 v; } t; t.u = *(const uint4*)p; return t.v;
}
__device__ __forceinline__ void glds16(const void* g, void* l){
    __builtin_amdgcn_global_load_lds((const __attribute__((address_space(1))) unsigned*)g,
                                     (__attribute__((address_space(3))) unsigned*)l, 16, 0, 0);
}

// merged fp32 -> bf16 convert for x (8192 blks), qkv_w (1536), proj_w (512)
__global__ __launch_bounds__(256) void cvt3_kernel(const float* __restrict__ x,
        const float* __restrict__ qw, const float* __restrict__ pw,
        unsigned short* __restrict__ xb, unsigned short* __restrict__ qwb,
        unsigned short* __restrict__ pwb)
{
    const int b = blockIdx.x;
    const float* src; unsigned short* dst; int off;
    if (b < 8192)       { src = x;  dst = xb;  off = b; }
    else if (b < 9728)  { src = qw; dst = qwb; off = b - 8192; }
    else                { src = pw; dst = pwb; off = b - 9728; }
    const int i = (off * 256 + threadIdx.x) * 8;
    float4 a = *(const float4*)(src + i);
    float4 c = *(const float4*)(src + i + 4);
    union { unsigned short u[8]; uint4 v; } t;
    t.u[0]=f2b(a.x); t.u[1]=f2b(a.y); t.u[2]=f2b(a.z); t.u[3]=f2b(a.w);
    t.u[4]=f2b(c.x); t.u[5]=f2b(c.y); t.u[6]=f2b(c.z); t.u[7]=f2b(c.w);
    *(uint4*)(dst + i) = t.v;
}

// ===== 256x256 GEMM (r6, best measured): BK=64, quadrant phases, vmcnt(6) =====
template<bool OUT_BF16>
__global__ __launch_bounds__(512, 2) void gemm256(const unsigned short* __restrict__ A,
        const unsigned short* __restrict__ Bw, const float* __restrict__ bias,
        void* __restrict__ Cp, int Nn)
{
    extern __shared__ unsigned short smem[];
    unsigned short* As = smem;            // [2][256][64] shorts
    unsigned short* Bs = smem + 32768;

    const int tid = threadIdx.x, lane = tid & 63;
    const int w = tid >> 6, wm = w >> 2, wn = w & 3;
    const int rl = lane & 15, kslot = lane >> 4;

    const int gx = gridDim.x;
    const int nwg = gx * gridDim.y;
    int id = blockIdx.y * gx + blockIdx.x;
    id = (id & 7) * (nwg >> 3) + (id >> 3);
    const int cBase = (id % gx) * 256;
    const int mBase = (id / gx) * 256;

    const int u = tid >> 3;
    const int seg8 = ((tid & 7) ^ (u & 7)) * 8;
    const unsigned short* Ag = A  + (size_t)(mBase + u) * KD + seg8;
    const unsigned short* Bg = Bw + (size_t)(cBase + (u >> 4) * 64 + (u & 15)) * KD + seg8;

    const int arow = (wm * 16 + rl) * 64;
    const int brow = (wn * 16 + rl) * 64;
    const int psg0 = (kslot ^ (rl & 7)) * 8;
    const int psg1 = ((kslot + 4) ^ (rl & 7)) * 8;

    f32x4 acc[8][4];
    #pragma unroll
    for (int m = 0; m < 8; m++)
        #pragma unroll
        for (int n = 0; n < 4; n++) acc[m][n] = (f32x4)0.f;

#define STAGE_AH0(bb, kk) { glds16(Ag + (kk),            As + (bb)*16384 + tid*8); \
                            glds16(Ag + 64*KD + (kk),    As + (bb)*16384 + 4096  + tid*8); }
#define STAGE_AH1(bb, kk) { glds16(Ag + 128*KD + (kk),   As + (bb)*16384 + 8192  + tid*8); \
                            glds16(Ag + 192*KD + (kk),   As + (bb)*16384 + 12288 + tid*8); }
#define STAGE_BH0(bb, kk) { glds16(Bg + (kk),            Bs + (bb)*16384 + tid*8); \
                            glds16(Bg + 16*KD + (kk),    Bs + (bb)*16384 + 4096  + tid*8); }
#define STAGE_BH1(bb, kk) { glds16(Bg + 32*KD + (kk),    Bs + (bb)*16384 + 8192  + tid*8); \
                            glds16(Bg + 48*KD + (kk),    Bs + (bb)*16384 + 12288 + tid*8); }

#define RDA(a_, half) { _Pragma("unroll") \
    for (int m = 0; m < 4; m++) { \
        af[m][0] = lds8((a_) + (half)*8192 + arow + m*2048 + psg0); \
        af[m][1] = lds8((a_) + (half)*8192 + arow + m*2048 + psg1); } }
#define RDB(b_, nlo, BF) { _Pragma("unroll") \
    for (int n = 0; n < 2; n++) { \
        BF[n][0] = lds8((b_) + brow + ((nlo)+n)*4096 + psg0); \
        BF[n][1] = lds8((b_) + brow + ((nlo)+n)*4096 + psg1); } }

#define MM16(mb, nb, BF) { \
    __builtin_amdgcn_s_setprio(1); \
    _Pragma("unroll") \
    for (int m = 0; m < 4; m++) \
        _Pragma("unroll") \
        for (int n = 0; n < 2; n++) { \
            acc[(mb)+m][(nb)+n] = __builtin_amdgcn_mfma_f32_16x16x32_bf16(af[m][0], BF[n][0], acc[(mb)+m][(nb)+n], 0, 0, 0); \
            acc[(mb)+m][(nb)+n] = __builtin_amdgcn_mfma_f32_16x16x32_bf16(af[m][1], BF[n][1], acc[(mb)+m][(nb)+n], 0, 0, 0); } \
    __builtin_amdgcn_s_setprio(0); }

#define VMC(N)  asm volatile("s_waitcnt vmcnt(" #N ")" ::: "memory");
#define BARR    __builtin_amdgcn_s_barrier();

    bf16x8 af[4][2], bfP[2][2], bfQ[2][2];

    STAGE_AH0(0, 0)
    STAGE_BH0(0, 0)
    STAGE_BH1(0, 0)
    STAGE_AH1(0, 0)

    int buf = 0;
    for (int t = 0; t < 15; ++t) {
        const unsigned short* a = As + buf * 16384;
        const unsigned short* b = Bs + buf * 16384;
        const int nk = (t + 1) * 64;
        STAGE_AH0(buf ^ 1, nk)
        VMC(6)
        BARR
        RDA(a, 0) RDB(b, 0, bfP)
        MM16(0, 0, bfP)
        STAGE_BH0(buf ^ 1, nk)
        VMC(6)
        BARR
        RDB(b, 2, bfQ)
        MM16(0, 2, bfQ)
        STAGE_BH1(buf ^ 1, nk)
        VMC(6)
        BARR
        RDA(a, 1)
        MM16(4, 0, bfP)
        STAGE_AH1(buf ^ 1, nk)
        MM16(4, 2, bfQ)
        buf ^= 1;
    }
    {
        const unsigned short* a = As + buf * 16384;
        const unsigned short* b = Bs + buf * 16384;
        VMC(4)
        BARR
        RDA(a, 0) RDB(b, 0, bfP)
        MM16(0, 0, bfP)
        VMC(2)
        BARR
        RDB(b, 2, bfQ)
        MM16(0, 2, bfQ)
        VMC(0)
        BARR
        RDA(a, 1)
        MM16(4, 0, bfP)
        MM16(4, 2, bfQ)
    }
#undef STAGE_AH0
#undef STAGE_AH1
#undef STAGE_BH0
#undef STAGE_BH1
#undef RDA
#undef RDB
#undef MM16
#undef VMC
#undef BARR

    float bv[4];
    #pragma unroll
    for (int n = 0; n < 4; n++) bv[n] = bias[cBase + wn * 64 + n * 16 + rl];
    #pragma unroll
    for (int m = 0; m < 8; m++) {
        #pragma unroll
        for (int i = 0; i < 4; i++) {
            const size_t row = mBase + (m >> 2) * 128 + (m & 3) * 32 + wm * 16 + kslot * 4 + i;
            #pragma unroll
            for (int n = 0; n < 4; n++) {
                const int col = cBase + wn * 64 + n * 16 + rl;
                const float val = acc[m][n][i] + bv[n];
                if (OUT_BF16) ((unsigned short*)Cp)[row * Nn + col] = f2b(val);
                else          ((float*)Cp)[row * Nn + col] = val;
            }
        }
    }
}

// Per-token head-attention. One wave per token, 4 tokens/block.
__global__ __launch_bounds__(256) void attn_kernel(const unsigned short* __restrict__ qkv,
                                                   unsigned short* __restrict__ outp)
{
    __shared__ __align__(16) unsigned short qs[4][48 * 72];
    __shared__ float ps[4][16 * 17];
    const int tid = threadIdx.x, w = tid >> 6, lane = tid & 63;
    const int t = blockIdx.x * 4 + w;

    const unsigned short* src = qkv + (size_t)t * NQKV;
    #pragma unroll
    for (int i = 0; i < 6; i++) {
        const int e = i * 512 + lane * 8;
        uint4 v = *(const uint4*)(src + e);
        *(uint4*)&qs[w][(e >> 6) * 72 + (e & 63)] = v;
    }
    __syncthreads();

    const int h = lane & 15, g0 = lane >> 4;
    uint4 qv[8];
    #pragma unroll
    for (int i = 0; i < 8; i++) qv[i] = *(const uint4*)&qs[w][h * 72 + i * 8];
    float s[4];
    #pragma unroll
    for (int i = 0; i < 4; i++) {
        const int g = g0 * 4 + i;
        float a = 0.f;
        #pragma unroll
        for (int c = 0; c < 8; c++) {
            uint4 kv = *(const uint4*)&qs[w][(16 + g) * 72 + c * 8];
            uint qa[4] = {qv[c].x, qv[c].y, qv[c].z, qv[c].w};
            uint ka[4] = {kv.x, kv.y, kv.z, kv.w};
            #pragma unroll
            for (int uu = 0; uu < 4; uu++) {
                a += b2f((unsigned short)qa[uu]) * b2f((unsigned short)ka[uu]);
                a += b2f((unsigned short)(qa[uu] >> 16)) * b2f((unsigned short)(ka[uu] >> 16));
            }
        }
        s[i] = a * ATT_SCALE;
    }
    float mx = fmaxf(fmaxf(s[0], s[1]), fmaxf(s[2], s[3]));
    mx = fmaxf(mx, __shfl_xor(mx, 16, 64));
    mx = fmaxf(mx, __shfl_xor(mx, 32, 64));
    float p[4], smv = 0.f;
    #pragma unroll
    for (int i = 0; i < 4; i++) { p[i] = __expf(s[i] - mx); smv += p[i]; }
    smv += __shfl_xor(smv, 16, 64);
    smv += __shfl_xor(smv, 32, 64);
    const float inv = 1.f / smv;
    #pragma unroll
    for (int i = 0; i < 4; i++) ps[w][h * 17 + g0 * 4 + i] = p[i] * inv;
    __syncthreads();

    const int h2 = lane >> 2, db = (lane & 3) * 16;
    float pr[16];
    #pragma unroll
    for (int g = 0; g < 16; g++) pr[g] = ps[w][h2 * 17 + g];
    float acc[16];
    #pragma unroll
    for (int j = 0; j < 16; j++) acc[j] = 0.f;
    #pragma unroll
    for (int g = 0; g < 16; g++) {
        const unsigned short* vp = &qs[w][(32 + g) * 72 + db];
        uint4 v0 = *(const uint4*)vp;
        uint4 v1 = *(const uint4*)(vp + 8);
        const float pg = pr[g];
        uint va[8] = {v0.x, v0.y, v0.z, v0.w, v1.x, v1.y, v1.z, v1.w};
        #pragma unroll
        for (int uu = 0; uu < 8; uu++) {
            acc[2*uu]   += pg * b2f((unsigned short)va[uu]);
            acc[2*uu+1] += pg * b2f((unsigned short)(va[uu] >> 16));
        }
    }
    const int b = t >> 12, n = t & 4095;
    const int n1 = h2 * 256 + (n >> 4);
    const int c0 = (n & 15) * 64 + db;
    union { unsigned short u[16]; uint4 v[2]; } st;
    #pragma unroll
    for (int j = 0; j < 16; j++) st.u[j] = f2b(acc[j]);
    unsigned short* dst = outp + ((size_t)(b * SEQL + n1)) * 1024 + c0;
    *(uint4*)dst       = st.v[0];
    *(uint4*)(dst + 8) = st.v[1];
}

extern "C" void kernel_launch(void* const* d_in, const int* in_sizes, int n_in,
                              void* d_out, int out_size, void* d_ws, size_t ws_size,
                              hipStream_t stream)
{
    const float* x      = (const float*)d_in[0];
    const float* qkv_w  = (const float*)d_in[1];
    const float* qkv_b  = (const float*)d_in[2];
    const float* proj_w = (const float*)d_in[3];
    const float* proj_b = (const float*)d_in[4];

    unsigned short* xb  = (unsigned short*)d_ws;            // 33.5 MB
    unsigned short* qkv = xb + (size_t)TOK * KD;            // 100.7 MB
    unsigned short* qwb = qkv + (size_t)TOK * NQKV;         // 6.3 MB
    unsigned short* pwb = qwb + (size_t)NQKV * KD;          // 2.1 MB
    unsigned short* att = xb;                               // alias (after QKV GEMM)

    hipFuncSetAttribute(reinterpret_cast<const void*>(&gemm256<true>),
                        hipFuncAttributeMaxDynamicSharedMemorySize, 131072);
    hipFuncSetAttribute(reinterpret_cast<const void*>(&gemm256<false>),
                        hipFuncAttributeMaxDynamicSharedMemorySize, 131072);

    cvt3_kernel<<<dim3(10240), dim3(256), 0, stream>>>(x, qkv_w, proj_w, xb, qwb, pwb);

    gemm256<true><<<dim3(NQKV / 256, TOK / 256), dim3(512), 131072, stream>>>(
        xb, qwb, qkv_b, qkv, NQKV);
    attn_kernel<<<dim3(TOK / 4), dim3(256), 0, stream>>>(qkv, att);
    gemm256<false><<<dim3(KD / 256, TOK / 256), dim3(512), 131072, stream>>>(
        att, pwb, proj_b, (float*)d_out, KD);
}